// Round 10
// baseline (369.862 us; speedup 1.0000x reference)
//
#include <hip/hip_runtime.h>
#include <cstdint>
#include <cstddef>

// ---------------------------------------------------------------------------
// GCN 2-layer: h = relu(Agg(x@W1)); out = relu(Agg(h@W3))
// Agg = D^-1/2 (A+I) D^-1/2. Identity: out[d] = relu(dinv[d]*(hs[d]+Σ hs[s]))
// with hs = (A@W)·dinv[row] fused into the GEMM epilogue.
// Layer-1 hs stored TILED: hs1_t[8][n][32] — eight 3.2MB column slices.
// agg256: tile = blockIdx%8 (round-robin blockIdx->XCD) so each XCD gathers
// only from its own L2-resident slice (escapes the ~3.5TB/s L2-miss fabric
// wall measured for the interleaved layout). Barrier-free, 8 nodes/block,
// 2 nodes/wave (one per 32-lane half), unroll-4 broadcast csr offsets.
// ---------------------------------------------------------------------------

#define NPART 128   // blocks for histogram/scatter phases

__device__ __forceinline__ float bf2f(unsigned short u) {
    union { unsigned int i; float f; } c; c.i = ((unsigned int)u) << 16; return c.f;
}
__device__ __forceinline__ unsigned short f2bf(float f) {
    union { float f; unsigned int i; } c; c.f = f;
    unsigned int r = c.i + 0x7fffu + ((c.i >> 16) & 1u);   // round-nearest-even
    return (unsigned short)(r >> 16);
}

// both weight transposes in one launch: W[K][N] fp32 -> Wt[N][K] bf16
__global__ __launch_bounds__(256) void wcvt2_kernel(const float* __restrict__ W1,
                                                    const float* __restrict__ W3,
                                                    unsigned short* __restrict__ W1t,
                                                    unsigned short* __restrict__ W3t) {
    int idx = blockIdx.x * 256 + threadIdx.x;
    if (idx < 256 * 256) {
        int nn = idx >> 8, kk = idx & 255;          // N=256, K=256
        W1t[idx] = f2bf(W1[kk * 256 + nn]);
    } else if (idx < 256 * 256 + 64 * 256) {
        int j = idx - 256 * 256;
        int nn = j >> 8, kk = j & 255;              // N=64, K=256
        W3t[j] = f2bf(W3[kk * 64 + nn]);
    }
}

// ---- graph build: bucket partition (64 nodes/bucket) ----------------------

__global__ __launch_bounds__(256) void part_hist(const int* __restrict__ dst, int E, int NB,
                                                 int* __restrict__ blockhist) {
    __shared__ int lh[1024];
    for (int t = threadIdx.x; t < NB; t += 256) lh[t] = 0;
    __syncthreads();
    const int per = (E + NPART - 1) / NPART;
    const int beg = blockIdx.x * per;
    const int end = min(E, beg + per);
    for (int i = beg + threadIdx.x; i < end; i += 256)
        atomicAdd(&lh[dst[i] >> 6], 1);
    __syncthreads();
    for (int t = threadIdx.x; t < NB; t += 256)
        blockhist[blockIdx.x * NB + t] = lh[t];
}

__global__ __launch_bounds__(1024) void part_scan(const int* __restrict__ blockhist,
                                                  int* __restrict__ bofs,
                                                  int* __restrict__ bbase, int NB) {
    __shared__ int wsum[16];
    const int t = threadIdx.x;
    const int lane = t & 63;
    int tot = 0;
    if (t < NB) {
        #pragma unroll 4
        for (int k = 0; k < NPART; ++k) tot += blockhist[k * NB + t];
    }
    int x = tot;
    #pragma unroll
    for (int off = 1; off < 64; off <<= 1) {
        int q = __shfl_up(x, off);
        if (lane >= off) x += q;
    }
    if (lane == 63) wsum[t >> 6] = x;
    __syncthreads();
    if (t < 64) {
        int y = (t < 16) ? wsum[t] : 0;
        #pragma unroll
        for (int off = 1; off < 16; off <<= 1) {
            int q = __shfl_up(y, off);
            if (lane >= off) y += q;
        }
        if (t < 16) wsum[t] = y;
    }
    __syncthreads();
    int excl = ((t >> 6) ? wsum[(t >> 6) - 1] : 0) + x - tot;
    if (t < NB) {
        bofs[t] = excl;
        if (t == NB - 1) bofs[NB] = excl + tot;
        int run = excl;
        for (int k = 0; k < NPART; ++k) {
            int c = blockhist[k * NB + t];
            bbase[k * NB + t] = run;
            run += c;
        }
    }
}

// scatter compressed edge words (src<<6 | dstLocal) into bucket regions
__global__ __launch_bounds__(256) void part_scatter(const int* __restrict__ src,
                                                    const int* __restrict__ dst,
                                                    const int* __restrict__ bbase,
                                                    unsigned int* __restrict__ words,
                                                    int E, int NB) {
    __shared__ int lbase[1024];
    for (int t = threadIdx.x; t < NB; t += 256) lbase[t] = bbase[blockIdx.x * NB + t];
    __syncthreads();
    const int per = (E + NPART - 1) / NPART;
    const int beg = blockIdx.x * per;
    const int end = min(E, beg + per);
    for (int i = beg + threadIdx.x; i < end; i += 256) {
        int d = dst[i];
        int off = atomicAdd(&lbase[d >> 6], 1);
        words[off] = ((unsigned)src[i] << 6) | (unsigned)(d & 63);
    }
}

// one block per bucket: local degrees -> rowptr, dinv, csr
__global__ __launch_bounds__(256) void bucket_build(const unsigned int* __restrict__ words,
                                                    const int* __restrict__ bofs,
                                                    int* __restrict__ rowptr,
                                                    float* __restrict__ dinv,
                                                    int* __restrict__ csr, int n) {
    const int b = blockIdx.x;
    const int node0 = b << 6;
    __shared__ int ldeg[64], lcur[64];
    if (threadIdx.x < 64) ldeg[threadIdx.x] = 0;
    __syncthreads();
    const int beg = bofs[b], end = bofs[b + 1];
    for (int i = beg + threadIdx.x; i < end; i += 256)
        atomicAdd(&ldeg[words[i] & 63u], 1);
    __syncthreads();
    if (threadIdx.x < 64) {
        const int lane = threadIdx.x;
        int v = ldeg[lane];
        int x = v;
        #pragma unroll
        for (int off = 1; off < 64; off <<= 1) {
            int q = __shfl_up(x, off);
            if (lane >= off) x += q;
        }
        int excl = x - v;
        int node = node0 + lane;
        if (node < n) {
            rowptr[node] = beg + excl;
            dinv[node] = rsqrtf((float)(v + 1));
        }
        lcur[lane] = beg + excl;
        if (b == (int)gridDim.x - 1 && lane == 0) rowptr[n] = end;
    }
    __syncthreads();
    for (int i = beg + threadIdx.x; i < end; i += 256) {
        unsigned int w = words[i];
        int pos = atomicAdd(&lcur[w & 63u], 1);
        csr[pos] = (int)(w >> 6);
    }
}

// ---- bf16 MFMA GEMM: C = (A @ Bt^T) * dinv[row] ---------------------------
// BM=128, BK=64, 256 threads (4 waves). AF32: fp32 A with fused bf16 cvt.
// CTILED: write C into tiled layout Ct[col>>5][row][col&31] (32-col slices).
template<int BN, int WM, int WN, bool AF32, bool CTILED>
__global__ __launch_bounds__(256) void mfma_gemm(const void* __restrict__ Av,
                                                 const unsigned short* __restrict__ Bt,
                                                 const float* __restrict__ dinvp,
                                                 unsigned short* __restrict__ C,
                                                 int M, int N, int K) {
    constexpr int BM = 128, BK = 64;
    constexpr int KP = 72;
    constexpr int WTM = BM / WM;
    constexpr int WTN = BN / WN;
    constexpr int MF = WTM / 16;
    constexpr int NF = WTN / 16;
    __shared__ unsigned short As[BM][KP];
    __shared__ unsigned short Bs[BN][KP];
    const int tid = threadIdx.x;
    const int wid = tid >> 6;
    const int lane = tid & 63;
    const int wr = wid / WN;
    const int wc = wid % WN;
    const int bm = blockIdx.y * BM;
    const int bn = blockIdx.x * BN;
    const int l15 = lane & 15;
    const int lg = lane >> 4;

    using bf16x8 = __attribute__((ext_vector_type(8))) short;
    using f32x4  = __attribute__((ext_vector_type(4))) float;
    f32x4 acc[MF][NF] = {};

    for (int k0 = 0; k0 < K; k0 += BK) {
        #pragma unroll
        for (int it = 0; it < (BM * BK / 8) / 256; ++it) {
            int v = tid + 256 * it;
            int row = v >> 3;
            int oct = v & 7;
            uint4 val = make_uint4(0, 0, 0, 0);
            int gr = bm + row;
            if (gr < M) {
                if (AF32) {
                    const float* A32 = (const float*)Av;
                    float4 f0 = *(const float4*)(A32 + (size_t)gr * K + k0 + oct * 8);
                    float4 f1 = *(const float4*)(A32 + (size_t)gr * K + k0 + oct * 8 + 4);
                    union { unsigned short u[8]; uint4 v4; } pk;
                    pk.u[0] = f2bf(f0.x); pk.u[1] = f2bf(f0.y);
                    pk.u[2] = f2bf(f0.z); pk.u[3] = f2bf(f0.w);
                    pk.u[4] = f2bf(f1.x); pk.u[5] = f2bf(f1.y);
                    pk.u[6] = f2bf(f1.z); pk.u[7] = f2bf(f1.w);
                    val = pk.v4;
                } else {
                    const unsigned short* Ab = (const unsigned short*)Av;
                    val = *(const uint4*)(Ab + (size_t)gr * K + k0 + oct * 8);
                }
            }
            *(uint4*)(&As[row][oct * 8]) = val;
        }
        #pragma unroll
        for (int it = 0; it < (BN * BK / 8) / 256; ++it) {
            int v = tid + 256 * it;
            int row = v >> 3;
            int oct = v & 7;
            uint4 val = *(const uint4*)(Bt + (size_t)(bn + row) * K + k0 + oct * 8);
            *(uint4*)(&Bs[row][oct * 8]) = val;
        }
        __syncthreads();
        #pragma unroll
        for (int kk = 0; kk < 2; ++kk) {
            bf16x8 af[MF], bfr[NF];
            #pragma unroll
            for (int m = 0; m < MF; ++m)
                af[m] = *(const bf16x8*)(&As[wr * WTM + m * 16 + l15][kk * 32 + lg * 8]);
            #pragma unroll
            for (int nf = 0; nf < NF; ++nf)
                bfr[nf] = *(const bf16x8*)(&Bs[wc * WTN + nf * 16 + l15][kk * 32 + lg * 8]);
            #pragma unroll
            for (int m = 0; m < MF; ++m)
                #pragma unroll
                for (int nf = 0; nf < NF; ++nf)
                    acc[m][nf] = __builtin_amdgcn_mfma_f32_16x16x32_bf16(
                        af[m], bfr[nf], acc[m][nf], 0, 0, 0);
        }
        __syncthreads();
    }
    // C/D layout: col=lane&15, row=(lane>>4)*4+reg  [HW-verified]
    #pragma unroll
    for (int m = 0; m < MF; ++m) {
        #pragma unroll
        for (int j = 0; j < 4; ++j) {
            int row = bm + wr * WTM + m * 16 + lg * 4 + j;
            if (row < M) {
                float s = dinvp[row];
                #pragma unroll
                for (int nf = 0; nf < NF; ++nf) {
                    int col = bn + wc * WTN + nf * 16 + l15;
                    unsigned short v = f2bf(acc[m][nf][j] * s);
                    if (CTILED)
                        C[((size_t)(col >> 5) * M + row) * 32 + (col & 31)] = v;
                    else
                        C[(size_t)row * N + col] = v;
                }
            }
        }
    }
}

// ---- agg256: XCD-affine tiled gather --------------------------------------
// hs tiled [8][n][32]. Block = (nodegroup g, tile t=blockIdx%8); 8 nodes.
// Wave w owns nodes d0+2w, d0+2w+1 (one per 32-lane half). Barrier-free.
// out[d][t*32+c] = relu(dinv[d]*(hs_t[t][d][c] + Σ hs_t[t][s][c]))  (bf16)
__global__ __launch_bounds__(256) void agg256_tiled(
        const unsigned short* __restrict__ hst, const int* __restrict__ rowptr,
        const int* __restrict__ csr, const float* __restrict__ dinv,
        unsigned short* __restrict__ out, int n) {
    const int t = blockIdx.x & 7;              // -> XCD (round-robin dispatch)
    const int g = blockIdx.x >> 3;
    const int wv = threadIdx.x >> 6;
    const int half = (threadIdx.x >> 5) & 1;
    const int c = threadIdx.x & 31;
    const int d = g * 8 + wv * 2 + half;
    if (d >= n) return;
    const unsigned short* slice = hst + (size_t)t * n * 32;

    float acc = bf2f(slice[(size_t)d * 32 + c]);      // self-loop (pre-scaled)
    const int beg = rowptr[d];
    const int deg = rowptr[d + 1] - beg;

    int k = 0;
    for (; k + 4 <= deg; k += 4) {
        int s0 = csr[beg + k];
        int s1 = csr[beg + k + 1];
        int s2 = csr[beg + k + 2];
        int s3 = csr[beg + k + 3];
        float v0 = bf2f(slice[(size_t)s0 * 32 + c]);
        float v1 = bf2f(slice[(size_t)s1 * 32 + c]);
        float v2 = bf2f(slice[(size_t)s2 * 32 + c]);
        float v3 = bf2f(slice[(size_t)s3 * 32 + c]);
        acc += (v0 + v1) + (v2 + v3);
    }
    for (; k < deg; ++k)
        acc += bf2f(slice[(size_t)csr[beg + k] * 32 + c]);

    out[(size_t)d * 256 + t * 32 + c] = f2bf(fmaxf(dinv[d] * acc, 0.f));
}

// ---- agg64: block-per-node pull (R9 proven) -------------------------------
__global__ __launch_bounds__(256) void aggregate64_kernel(
        const unsigned short* __restrict__ hs, const int* __restrict__ rowptr,
        const int* __restrict__ csr, const float* __restrict__ dinv,
        float* __restrict__ out, int n) {
    const int d = blockIdx.x;
    const int tid = threadIdx.x;
    const int wid = tid >> 6;
    const int lane = tid & 63;
    const int beg = rowptr[d];
    const int end = rowptr[d + 1];

    float acc = 0.f;
    if (wid == 0) acc = bf2f(hs[(size_t)d * 64 + lane]);   // self-loop

    __shared__ unsigned int soff[256];
    const char* hb = (const char*)hs;
    for (int k0 = beg; k0 < end; k0 += 256) {
        int cnt = min(256, end - k0);
        if (tid < cnt) soff[tid] = (unsigned)csr[k0 + tid] * 128u;
        __syncthreads();
        #pragma unroll 8
        for (int e = wid; e < cnt; e += 4) {
            unsigned short t = *(const unsigned short*)(hb + soff[e] + lane * 2);
            acc += bf2f(t);
        }
        __syncthreads();
    }

    __shared__ float part[3][64];
    if (wid > 0) part[wid - 1][lane] = acc;
    __syncthreads();
    if (wid == 0) {
        acc += part[0][lane] + part[1][lane] + part[2][lane];
        out[(size_t)d * 64 + lane] = fmaxf(dinv[d] * acc, 0.f);
    }
}

// ---------------------------------------------------------------------------

static inline size_t align256(size_t v) { return (v + 255) & ~(size_t)255; }

extern "C" void kernel_launch(void* const* d_in, const int* in_sizes, int n_in,
                              void* d_out, int out_size, void* d_ws, size_t ws_size,
                              hipStream_t stream) {
    const float* x  = (const float*)d_in[0];
    const int*   ei = (const int*)d_in[1];
    const float* W1 = (const float*)d_in[2];
    const float* W3 = (const float*)d_in[3];

    const int n = in_sizes[0] / 256;     // 50000
    const int E = in_sizes[1] / 2;       // 1600000
    const int NB = (n + 63) >> 6;        // 782 buckets
    const int* src = ei;
    const int* dst = ei + E;

    char* w = (char*)d_ws;
    auto alloc = [&](size_t bytes) { char* p = w; w += align256(bytes); return p; };
    unsigned short* hs1t = (unsigned short*)alloc((size_t)n * 256 * 2);  // tiled [8][n][32]
    unsigned short* a1   = (unsigned short*)alloc((size_t)n * 256 * 2);
    unsigned short* hs2  = (unsigned short*)alloc((size_t)n * 64 * 2);
    unsigned short* W1t  = (unsigned short*)alloc(256 * 256 * 2);
    unsigned short* W3t  = (unsigned short*)alloc(64 * 256 * 2);
    float* dinv          = (float*)alloc((size_t)n * 4);
    int*   rowptr        = (int*)alloc((size_t)(n + 1) * 4);
    int*   csr           = (int*)alloc((size_t)E * 4);
    unsigned int* words  = (unsigned int*)alloc((size_t)E * 4);
    int*   blockhist     = (int*)alloc((size_t)NPART * NB * 4);
    int*   bbase         = (int*)alloc((size_t)NPART * NB * 4);
    int*   bofs          = (int*)alloc((size_t)(NB + 1) * 4);
    float* out           = (float*)d_out;

    wcvt2_kernel<<<(256 * 256 + 64 * 256 + 255) / 256, 256, 0, stream>>>(W1, W3, W1t, W3t);

    part_hist<<<NPART, 256, 0, stream>>>(dst, E, NB, blockhist);
    part_scan<<<1, 1024, 0, stream>>>(blockhist, bofs, bbase, NB);
    part_scatter<<<NPART, 256, 0, stream>>>(src, dst, bbase, words, E, NB);
    bucket_build<<<NB, 256, 0, stream>>>(words, bofs, rowptr, dinv, csr, n);

    // layer 1: hs1t = tiled bf16((x @ W1)·dinv); a1 = relu-agg (bf16, row-major)
    {
        dim3 grid(1, (n + 127) / 128);
        mfma_gemm<256, 2, 2, true, true><<<grid, 256, 0, stream>>>(x, W1t, dinv, hs1t, n, 256, 256);
        int ngrp = (n + 7) / 8;
        agg256_tiled<<<ngrp * 8, 256, 0, stream>>>(hs1t, rowptr, csr, dinv, a1, n);
    }
    // layer 2: hs2 = bf16((a1 @ W3)·dinv); out = relu-agg (fp32)
    {
        dim3 grid(1, (n + 127) / 128);
        mfma_gemm<64, 4, 1, false, false><<<grid, 256, 0, stream>>>(a1, W3t, dinv, hs2, n, 64, 256);
        aggregate64_kernel<<<n, 256, 0, stream>>>(hs2, rowptr, csr, dinv, out, n);
    }
}

// Round 11
// 361.581 us; speedup vs baseline: 1.0229x; 1.0229x over previous
//
#include <hip/hip_runtime.h>
#include <cstdint>
#include <cstddef>

// ---------------------------------------------------------------------------
// GCN 2-layer: h = relu(Agg(x@W1)); out = relu(Agg(h@W3))
// Agg = D^-1/2 (A+I) D^-1/2. Identity: out[d] = relu(dinv[d]*(hs[d]+Σ hs[s]))
// with hs = (A@W)·dinv[row] fused into the GEMM epilogue.
// Layer-1 hs stored TILED: hs1_t[8][n][32] — eight 3.2MB column slices, each
// L2-resident on its XCD (tile = blockIdx%8, round-robin dispatch). R10 proved
// the locality (FETCH 359->48MB); this round restores fat gathers: one wave
// per (node,tile), 8 edges x 64B aligned segments = 512B per load instruction,
// cross-group shfl_xor reduce at the end.
// ---------------------------------------------------------------------------

#define NPART 128   // blocks for histogram/scatter phases

__device__ __forceinline__ float bf2f(unsigned short u) {
    union { unsigned int i; float f; } c; c.i = ((unsigned int)u) << 16; return c.f;
}
__device__ __forceinline__ unsigned short f2bf(float f) {
    union { float f; unsigned int i; } c; c.f = f;
    unsigned int r = c.i + 0x7fffu + ((c.i >> 16) & 1u);   // round-nearest-even
    return (unsigned short)(r >> 16);
}

// both weight transposes in one launch: W[K][N] fp32 -> Wt[N][K] bf16
__global__ __launch_bounds__(256) void wcvt2_kernel(const float* __restrict__ W1,
                                                    const float* __restrict__ W3,
                                                    unsigned short* __restrict__ W1t,
                                                    unsigned short* __restrict__ W3t) {
    int idx = blockIdx.x * 256 + threadIdx.x;
    if (idx < 256 * 256) {
        int nn = idx >> 8, kk = idx & 255;          // N=256, K=256
        W1t[idx] = f2bf(W1[kk * 256 + nn]);
    } else if (idx < 256 * 256 + 64 * 256) {
        int j = idx - 256 * 256;
        int nn = j >> 8, kk = j & 255;              // N=64, K=256
        W3t[j] = f2bf(W3[kk * 64 + nn]);
    }
}

// ---- graph build: bucket partition (64 nodes/bucket) ----------------------

__global__ __launch_bounds__(256) void part_hist(const int* __restrict__ dst, int E, int NB,
                                                 int* __restrict__ blockhist) {
    __shared__ int lh[1024];
    for (int t = threadIdx.x; t < NB; t += 256) lh[t] = 0;
    __syncthreads();
    const int per = (E + NPART - 1) / NPART;
    const int beg = blockIdx.x * per;
    const int end = min(E, beg + per);
    for (int i = beg + threadIdx.x; i < end; i += 256)
        atomicAdd(&lh[dst[i] >> 6], 1);
    __syncthreads();
    for (int t = threadIdx.x; t < NB; t += 256)
        blockhist[blockIdx.x * NB + t] = lh[t];
}

__global__ __launch_bounds__(1024) void part_scan(const int* __restrict__ blockhist,
                                                  int* __restrict__ bofs,
                                                  int* __restrict__ bbase, int NB) {
    __shared__ int wsum[16];
    const int t = threadIdx.x;
    const int lane = t & 63;
    int tot = 0;
    if (t < NB) {
        #pragma unroll 4
        for (int k = 0; k < NPART; ++k) tot += blockhist[k * NB + t];
    }
    int x = tot;
    #pragma unroll
    for (int off = 1; off < 64; off <<= 1) {
        int q = __shfl_up(x, off);
        if (lane >= off) x += q;
    }
    if (lane == 63) wsum[t >> 6] = x;
    __syncthreads();
    if (t < 64) {
        int y = (t < 16) ? wsum[t] : 0;
        #pragma unroll
        for (int off = 1; off < 16; off <<= 1) {
            int q = __shfl_up(y, off);
            if (lane >= off) y += q;
        }
        if (t < 16) wsum[t] = y;
    }
    __syncthreads();
    int excl = ((t >> 6) ? wsum[(t >> 6) - 1] : 0) + x - tot;
    if (t < NB) {
        bofs[t] = excl;
        if (t == NB - 1) bofs[NB] = excl + tot;
        int run = excl;
        for (int k = 0; k < NPART; ++k) {
            int c = blockhist[k * NB + t];
            bbase[k * NB + t] = run;
            run += c;
        }
    }
}

// scatter compressed edge words (src<<6 | dstLocal) into bucket regions
__global__ __launch_bounds__(256) void part_scatter(const int* __restrict__ src,
                                                    const int* __restrict__ dst,
                                                    const int* __restrict__ bbase,
                                                    unsigned int* __restrict__ words,
                                                    int E, int NB) {
    __shared__ int lbase[1024];
    for (int t = threadIdx.x; t < NB; t += 256) lbase[t] = bbase[blockIdx.x * NB + t];
    __syncthreads();
    const int per = (E + NPART - 1) / NPART;
    const int beg = blockIdx.x * per;
    const int end = min(E, beg + per);
    for (int i = beg + threadIdx.x; i < end; i += 256) {
        int d = dst[i];
        int off = atomicAdd(&lbase[d >> 6], 1);
        words[off] = ((unsigned)src[i] << 6) | (unsigned)(d & 63);
    }
}

// one block per bucket: local degrees -> rowptr, dinv, csr
__global__ __launch_bounds__(256) void bucket_build(const unsigned int* __restrict__ words,
                                                    const int* __restrict__ bofs,
                                                    int* __restrict__ rowptr,
                                                    float* __restrict__ dinv,
                                                    int* __restrict__ csr, int n) {
    const int b = blockIdx.x;
    const int node0 = b << 6;
    __shared__ int ldeg[64], lcur[64];
    if (threadIdx.x < 64) ldeg[threadIdx.x] = 0;
    __syncthreads();
    const int beg = bofs[b], end = bofs[b + 1];
    for (int i = beg + threadIdx.x; i < end; i += 256)
        atomicAdd(&ldeg[words[i] & 63u], 1);
    __syncthreads();
    if (threadIdx.x < 64) {
        const int lane = threadIdx.x;
        int v = ldeg[lane];
        int x = v;
        #pragma unroll
        for (int off = 1; off < 64; off <<= 1) {
            int q = __shfl_up(x, off);
            if (lane >= off) x += q;
        }
        int excl = x - v;
        int node = node0 + lane;
        if (node < n) {
            rowptr[node] = beg + excl;
            dinv[node] = rsqrtf((float)(v + 1));
        }
        lcur[lane] = beg + excl;
        if (b == (int)gridDim.x - 1 && lane == 0) rowptr[n] = end;
    }
    __syncthreads();
    for (int i = beg + threadIdx.x; i < end; i += 256) {
        unsigned int w = words[i];
        int pos = atomicAdd(&lcur[w & 63u], 1);
        csr[pos] = (int)(w >> 6);
    }
}

// ---- bf16 MFMA GEMM: C = (A @ Bt^T) * dinv[row] ---------------------------
// BM=128, BK=64, 256 threads (4 waves). AF32: fp32 A with fused bf16 cvt.
// CTILED: write C into tiled layout Ct[col>>5][row][col&31] (32-col slices).
template<int BN, int WM, int WN, bool AF32, bool CTILED>
__global__ __launch_bounds__(256) void mfma_gemm(const void* __restrict__ Av,
                                                 const unsigned short* __restrict__ Bt,
                                                 const float* __restrict__ dinvp,
                                                 unsigned short* __restrict__ C,
                                                 int M, int N, int K) {
    constexpr int BM = 128, BK = 64;
    constexpr int KP = 72;
    constexpr int WTM = BM / WM;
    constexpr int WTN = BN / WN;
    constexpr int MF = WTM / 16;
    constexpr int NF = WTN / 16;
    __shared__ unsigned short As[BM][KP];
    __shared__ unsigned short Bs[BN][KP];
    const int tid = threadIdx.x;
    const int wid = tid >> 6;
    const int lane = tid & 63;
    const int wr = wid / WN;
    const int wc = wid % WN;
    const int bm = blockIdx.y * BM;
    const int bn = blockIdx.x * BN;
    const int l15 = lane & 15;
    const int lg = lane >> 4;

    using bf16x8 = __attribute__((ext_vector_type(8))) short;
    using f32x4  = __attribute__((ext_vector_type(4))) float;
    f32x4 acc[MF][NF] = {};

    for (int k0 = 0; k0 < K; k0 += BK) {
        #pragma unroll
        for (int it = 0; it < (BM * BK / 8) / 256; ++it) {
            int v = tid + 256 * it;
            int row = v >> 3;
            int oct = v & 7;
            uint4 val = make_uint4(0, 0, 0, 0);
            int gr = bm + row;
            if (gr < M) {
                if (AF32) {
                    const float* A32 = (const float*)Av;
                    float4 f0 = *(const float4*)(A32 + (size_t)gr * K + k0 + oct * 8);
                    float4 f1 = *(const float4*)(A32 + (size_t)gr * K + k0 + oct * 8 + 4);
                    union { unsigned short u[8]; uint4 v4; } pk;
                    pk.u[0] = f2bf(f0.x); pk.u[1] = f2bf(f0.y);
                    pk.u[2] = f2bf(f0.z); pk.u[3] = f2bf(f0.w);
                    pk.u[4] = f2bf(f1.x); pk.u[5] = f2bf(f1.y);
                    pk.u[6] = f2bf(f1.z); pk.u[7] = f2bf(f1.w);
                    val = pk.v4;
                } else {
                    const unsigned short* Ab = (const unsigned short*)Av;
                    val = *(const uint4*)(Ab + (size_t)gr * K + k0 + oct * 8);
                }
            }
            *(uint4*)(&As[row][oct * 8]) = val;
        }
        #pragma unroll
        for (int it = 0; it < (BN * BK / 8) / 256; ++it) {
            int v = tid + 256 * it;
            int row = v >> 3;
            int oct = v & 7;
            uint4 val = *(const uint4*)(Bt + (size_t)(bn + row) * K + k0 + oct * 8);
            *(uint4*)(&Bs[row][oct * 8]) = val;
        }
        __syncthreads();
        #pragma unroll
        for (int kk = 0; kk < 2; ++kk) {
            bf16x8 af[MF], bfr[NF];
            #pragma unroll
            for (int m = 0; m < MF; ++m)
                af[m] = *(const bf16x8*)(&As[wr * WTM + m * 16 + l15][kk * 32 + lg * 8]);
            #pragma unroll
            for (int nf = 0; nf < NF; ++nf)
                bfr[nf] = *(const bf16x8*)(&Bs[wc * WTN + nf * 16 + l15][kk * 32 + lg * 8]);
            #pragma unroll
            for (int m = 0; m < MF; ++m)
                #pragma unroll
                for (int nf = 0; nf < NF; ++nf)
                    acc[m][nf] = __builtin_amdgcn_mfma_f32_16x16x32_bf16(
                        af[m], bfr[nf], acc[m][nf], 0, 0, 0);
        }
        __syncthreads();
    }
    // C/D layout: col=lane&15, row=(lane>>4)*4+reg  [HW-verified]
    #pragma unroll
    for (int m = 0; m < MF; ++m) {
        #pragma unroll
        for (int j = 0; j < 4; ++j) {
            int row = bm + wr * WTM + m * 16 + lg * 4 + j;
            if (row < M) {
                float s = dinvp[row];
                #pragma unroll
                for (int nf = 0; nf < NF; ++nf) {
                    int col = bn + wc * WTN + nf * 16 + l15;
                    unsigned short v = f2bf(acc[m][nf][j] * s);
                    if (CTILED)
                        C[((size_t)(col >> 5) * M + row) * 32 + (col & 31)] = v;
                    else
                        C[(size_t)row * N + col] = v;
                }
            }
        }
    }
}

// ---- agg256: XCD-affine tiled gather, 8 edges / 512B per instruction ------
// hs tiled [8][n][32]. One wave per (node, tile); tile = blockIdx%8.
// Lane = (grp=lane>>3, j=lane&7): group grp takes edge k+grp, loads ushort4
// (cols j*4..j*4+3 of the 64B slice row). Cross-group reduce: shfl_xor 8/16/32.
__global__ __launch_bounds__(256) void agg256_tiled(
        const unsigned short* __restrict__ hst, const int* __restrict__ rowptr,
        const int* __restrict__ csr, const float* __restrict__ dinv,
        unsigned short* __restrict__ out, int n) {
    const int t = blockIdx.x & 7;              // -> XCD (round-robin dispatch)
    const int g4 = blockIdx.x >> 3;
    const int wv = threadIdx.x >> 6;
    const int lane = threadIdx.x & 63;
    const int grp = lane >> 3;                 // edge slot 0..7
    const int j = lane & 7;                    // col quad 0..7
    const int d = g4 * 4 + wv;
    if (d >= n) return;
    const char* sb = (const char*)(hst + (size_t)t * n * 32);

    float a0 = 0.f, a1 = 0.f, a2 = 0.f, a3 = 0.f;
    if (grp == 0) {   // self-loop counted once after cross-group reduce
        ushort4 v = *(const ushort4*)(sb + (size_t)d * 64 + j * 8);
        a0 = bf2f(v.x); a1 = bf2f(v.y); a2 = bf2f(v.z); a3 = bf2f(v.w);
    }

    const int beg = rowptr[d];
    const int deg = rowptr[d + 1] - beg;
    int k = 0;
    #pragma unroll 2
    for (; k + 8 <= deg; k += 8) {
        int s = csr[beg + k + grp];            // 32B window, 8-lane broadcast
        ushort4 v = *(const ushort4*)(sb + (size_t)s * 64 + j * 8);
        a0 += bf2f(v.x); a1 += bf2f(v.y);
        a2 += bf2f(v.z); a3 += bf2f(v.w);
    }
    if (k < deg) {                             // tail (masked)
        if (k + grp < deg) {
            int s = csr[beg + k + grp];
            ushort4 v = *(const ushort4*)(sb + (size_t)s * 64 + j * 8);
            a0 += bf2f(v.x); a1 += bf2f(v.y);
            a2 += bf2f(v.z); a3 += bf2f(v.w);
        }
    }

    #pragma unroll
    for (int off = 8; off < 64; off <<= 1) {
        a0 += __shfl_xor(a0, off);
        a1 += __shfl_xor(a1, off);
        a2 += __shfl_xor(a2, off);
        a3 += __shfl_xor(a3, off);
    }
    if (grp == 0) {
        const float wd = dinv[d];
        union { unsigned short u[4]; uint2 v; } pk;
        pk.u[0] = f2bf(fmaxf(wd * a0, 0.f));
        pk.u[1] = f2bf(fmaxf(wd * a1, 0.f));
        pk.u[2] = f2bf(fmaxf(wd * a2, 0.f));
        pk.u[3] = f2bf(fmaxf(wd * a3, 0.f));
        *(uint2*)(out + (size_t)d * 256 + t * 32 + j * 4) = pk.v;
    }
}

// ---- agg64: block-per-node pull (R9 proven) -------------------------------
__global__ __launch_bounds__(256) void aggregate64_kernel(
        const unsigned short* __restrict__ hs, const int* __restrict__ rowptr,
        const int* __restrict__ csr, const float* __restrict__ dinv,
        float* __restrict__ out, int n) {
    const int d = blockIdx.x;
    const int tid = threadIdx.x;
    const int wid = tid >> 6;
    const int lane = tid & 63;
    const int beg = rowptr[d];
    const int end = rowptr[d + 1];

    float acc = 0.f;
    if (wid == 0) acc = bf2f(hs[(size_t)d * 64 + lane]);   // self-loop

    __shared__ unsigned int soff[256];
    const char* hb = (const char*)hs;
    for (int k0 = beg; k0 < end; k0 += 256) {
        int cnt = min(256, end - k0);
        if (tid < cnt) soff[tid] = (unsigned)csr[k0 + tid] * 128u;
        __syncthreads();
        #pragma unroll 8
        for (int e = wid; e < cnt; e += 4) {
            unsigned short t = *(const unsigned short*)(hb + soff[e] + lane * 2);
            acc += bf2f(t);
        }
        __syncthreads();
    }

    __shared__ float part[3][64];
    if (wid > 0) part[wid - 1][lane] = acc;
    __syncthreads();
    if (wid == 0) {
        acc += part[0][lane] + part[1][lane] + part[2][lane];
        out[(size_t)d * 64 + lane] = fmaxf(dinv[d] * acc, 0.f);
    }
}

// ---------------------------------------------------------------------------

static inline size_t align256(size_t v) { return (v + 255) & ~(size_t)255; }

extern "C" void kernel_launch(void* const* d_in, const int* in_sizes, int n_in,
                              void* d_out, int out_size, void* d_ws, size_t ws_size,
                              hipStream_t stream) {
    const float* x  = (const float*)d_in[0];
    const int*   ei = (const int*)d_in[1];
    const float* W1 = (const float*)d_in[2];
    const float* W3 = (const float*)d_in[3];

    const int n = in_sizes[0] / 256;     // 50000
    const int E = in_sizes[1] / 2;       // 1600000
    const int NB = (n + 63) >> 6;        // 782 buckets
    const int* src = ei;
    const int* dst = ei + E;

    char* w = (char*)d_ws;
    auto alloc = [&](size_t bytes) { char* p = w; w += align256(bytes); return p; };
    unsigned short* hs1t = (unsigned short*)alloc((size_t)n * 256 * 2);  // tiled [8][n][32]
    unsigned short* a1   = (unsigned short*)alloc((size_t)n * 256 * 2);
    unsigned short* hs2  = (unsigned short*)alloc((size_t)n * 64 * 2);
    unsigned short* W1t  = (unsigned short*)alloc(256 * 256 * 2);
    unsigned short* W3t  = (unsigned short*)alloc(64 * 256 * 2);
    float* dinv          = (float*)alloc((size_t)n * 4);
    int*   rowptr        = (int*)alloc((size_t)(n + 1) * 4);
    int*   csr           = (int*)alloc((size_t)E * 4);
    unsigned int* words  = (unsigned int*)alloc((size_t)E * 4);
    int*   blockhist     = (int*)alloc((size_t)NPART * NB * 4);
    int*   bbase         = (int*)alloc((size_t)NPART * NB * 4);
    int*   bofs          = (int*)alloc((size_t)(NB + 1) * 4);
    float* out           = (float*)d_out;

    wcvt2_kernel<<<(256 * 256 + 64 * 256 + 255) / 256, 256, 0, stream>>>(W1, W3, W1t, W3t);

    part_hist<<<NPART, 256, 0, stream>>>(dst, E, NB, blockhist);
    part_scan<<<1, 1024, 0, stream>>>(blockhist, bofs, bbase, NB);
    part_scatter<<<NPART, 256, 0, stream>>>(src, dst, bbase, words, E, NB);
    bucket_build<<<NB, 256, 0, stream>>>(words, bofs, rowptr, dinv, csr, n);

    // layer 1: hs1t = tiled bf16((x @ W1)·dinv); a1 = relu-agg (bf16, row-major)
    {
        dim3 grid(1, (n + 127) / 128);
        mfma_gemm<256, 2, 2, true, true><<<grid, 256, 0, stream>>>(x, W1t, dinv, hs1t, n, 256, 256);
        int ngrp = (n + 3) / 4;
        agg256_tiled<<<ngrp * 8, 256, 0, stream>>>(hs1t, rowptr, csr, dinv, a1, n);
    }
    // layer 2: hs2 = bf16((a1 @ W3)·dinv); out = relu-agg (fp32)
    {
        dim3 grid(1, (n + 127) / 128);
        mfma_gemm<64, 4, 1, false, false><<<grid, 256, 0, stream>>>(a1, W3t, dinv, hs2, n, 64, 256);
        aggregate64_kernel<<<n, 256, 0, stream>>>(hs2, rowptr, csr, dinv, out, n);
    }
}

// Round 12
// 308.979 us; speedup vs baseline: 1.1970x; 1.1702x over previous
//
#include <hip/hip_runtime.h>
#include <cstdint>
#include <cstddef>

// ---------------------------------------------------------------------------
// GCN 2-layer: h = relu(Agg(x@W1)); out = relu(Agg(h@W3))
// Agg = D^-1/2 (A+I) D^-1/2. Identity: out[d] = relu(dinv[d]*(hs[d]+Σ hs[s]))
// with hs = (A@W)·dinv[row] fused into the GEMM epilogue.
// GEMMs: bf16 MFMA 16x16x32, fp32 acc. Aggregation: block-per-node pull,
// LDS-staged edge offsets, 512B wave-gathers, unroll 8 — pinned at the
// ~3.5 TB/s beyond-L2 random-gather fabric wall (proven floor across
// R4/R5/R6/R8/R10/R11 alternatives; XCD-tiled variants trade fabric wait
// for instruction issue at >=167us and lose).
// Edges: 4B words (src<<6 | dstLocal), bucketed by dst>>6 (64 nodes/bucket).
// ---------------------------------------------------------------------------

#define NPART 128   // blocks for histogram/scatter phases

__device__ __forceinline__ float bf2f(unsigned short u) {
    union { unsigned int i; float f; } c; c.i = ((unsigned int)u) << 16; return c.f;
}
__device__ __forceinline__ unsigned short f2bf(float f) {
    union { float f; unsigned int i; } c; c.f = f;
    unsigned int r = c.i + 0x7fffu + ((c.i >> 16) & 1u);   // round-nearest-even
    return (unsigned short)(r >> 16);
}

// both weight transposes in one launch: W[K][N] fp32 -> Wt[N][K] bf16
__global__ __launch_bounds__(256) void wcvt2_kernel(const float* __restrict__ W1,
                                                    const float* __restrict__ W3,
                                                    unsigned short* __restrict__ W1t,
                                                    unsigned short* __restrict__ W3t) {
    int idx = blockIdx.x * 256 + threadIdx.x;
    if (idx < 256 * 256) {
        int nn = idx >> 8, kk = idx & 255;          // N=256, K=256
        W1t[idx] = f2bf(W1[kk * 256 + nn]);
    } else if (idx < 256 * 256 + 64 * 256) {
        int j = idx - 256 * 256;
        int nn = j >> 8, kk = j & 255;              // N=64, K=256
        W3t[j] = f2bf(W3[kk * 64 + nn]);
    }
}

// ---- graph build: bucket partition (64 nodes/bucket) ----------------------

__global__ __launch_bounds__(256) void part_hist(const int* __restrict__ dst, int E, int NB,
                                                 int* __restrict__ blockhist) {
    __shared__ int lh[1024];
    for (int t = threadIdx.x; t < NB; t += 256) lh[t] = 0;
    __syncthreads();
    const int per = (E + NPART - 1) / NPART;
    const int beg = blockIdx.x * per;
    const int end = min(E, beg + per);
    for (int i = beg + threadIdx.x; i < end; i += 256)
        atomicAdd(&lh[dst[i] >> 6], 1);
    __syncthreads();
    for (int t = threadIdx.x; t < NB; t += 256)
        blockhist[blockIdx.x * NB + t] = lh[t];
}

__global__ __launch_bounds__(1024) void part_scan(const int* __restrict__ blockhist,
                                                  int* __restrict__ bofs,
                                                  int* __restrict__ bbase, int NB) {
    __shared__ int wsum[16];
    const int t = threadIdx.x;
    const int lane = t & 63;
    int tot = 0;
    if (t < NB) {
        #pragma unroll 4
        for (int k = 0; k < NPART; ++k) tot += blockhist[k * NB + t];
    }
    int x = tot;
    #pragma unroll
    for (int off = 1; off < 64; off <<= 1) {
        int q = __shfl_up(x, off);
        if (lane >= off) x += q;
    }
    if (lane == 63) wsum[t >> 6] = x;
    __syncthreads();
    if (t < 64) {
        int y = (t < 16) ? wsum[t] : 0;
        #pragma unroll
        for (int off = 1; off < 16; off <<= 1) {
            int q = __shfl_up(y, off);
            if (lane >= off) y += q;
        }
        if (t < 16) wsum[t] = y;
    }
    __syncthreads();
    int excl = ((t >> 6) ? wsum[(t >> 6) - 1] : 0) + x - tot;
    if (t < NB) {
        bofs[t] = excl;
        if (t == NB - 1) bofs[NB] = excl + tot;
        int run = excl;
        for (int k = 0; k < NPART; ++k) {
            int c = blockhist[k * NB + t];
            bbase[k * NB + t] = run;
            run += c;
        }
    }
}

// scatter compressed edge words (src<<6 | dstLocal) into bucket regions
__global__ __launch_bounds__(256) void part_scatter(const int* __restrict__ src,
                                                    const int* __restrict__ dst,
                                                    const int* __restrict__ bbase,
                                                    unsigned int* __restrict__ words,
                                                    int E, int NB) {
    __shared__ int lbase[1024];
    for (int t = threadIdx.x; t < NB; t += 256) lbase[t] = bbase[blockIdx.x * NB + t];
    __syncthreads();
    const int per = (E + NPART - 1) / NPART;
    const int beg = blockIdx.x * per;
    const int end = min(E, beg + per);
    for (int i = beg + threadIdx.x; i < end; i += 256) {
        int d = dst[i];
        int off = atomicAdd(&lbase[d >> 6], 1);
        words[off] = ((unsigned)src[i] << 6) | (unsigned)(d & 63);
    }
}

// one block per bucket: local degrees -> rowptr, dinv, csr (src-only, sorted by dst)
__global__ __launch_bounds__(256) void bucket_build(const unsigned int* __restrict__ words,
                                                    const int* __restrict__ bofs,
                                                    int* __restrict__ rowptr,
                                                    float* __restrict__ dinv,
                                                    int* __restrict__ csr, int n) {
    const int b = blockIdx.x;
    const int node0 = b << 6;
    __shared__ int ldeg[64], lcur[64];
    if (threadIdx.x < 64) ldeg[threadIdx.x] = 0;
    __syncthreads();
    const int beg = bofs[b], end = bofs[b + 1];
    for (int i = beg + threadIdx.x; i < end; i += 256)
        atomicAdd(&ldeg[words[i] & 63u], 1);
    __syncthreads();
    if (threadIdx.x < 64) {
        const int lane = threadIdx.x;
        int v = ldeg[lane];
        int x = v;
        #pragma unroll
        for (int off = 1; off < 64; off <<= 1) {
            int q = __shfl_up(x, off);
            if (lane >= off) x += q;
        }
        int excl = x - v;
        int node = node0 + lane;
        if (node < n) {
            rowptr[node] = beg + excl;
            dinv[node] = rsqrtf((float)(v + 1));
        }
        lcur[lane] = beg + excl;
        if (b == (int)gridDim.x - 1 && lane == 0) rowptr[n] = end;
    }
    __syncthreads();
    for (int i = beg + threadIdx.x; i < end; i += 256) {
        unsigned int w = words[i];
        int pos = atomicAdd(&lcur[w & 63u], 1);
        csr[pos] = (int)(w >> 6);
    }
}

// ---- bf16 MFMA GEMM: C[M,N] = (A[M,K] @ Bt[N,K]^T) * dinv[row] ------------
// BM=128, BK=64, 256 threads (4 waves). AF32: fp32 A with fused bf16 cvt.
template<int BN, int WM, int WN, bool AF32>
__global__ __launch_bounds__(256) void mfma_gemm(const void* __restrict__ Av,
                                                 const unsigned short* __restrict__ Bt,
                                                 const float* __restrict__ dinvp,
                                                 unsigned short* __restrict__ C,
                                                 int M, int N, int K) {
    constexpr int BM = 128, BK = 64;
    constexpr int KP = 72;
    constexpr int WTM = BM / WM;
    constexpr int WTN = BN / WN;
    constexpr int MF = WTM / 16;
    constexpr int NF = WTN / 16;
    __shared__ unsigned short As[BM][KP];
    __shared__ unsigned short Bs[BN][KP];
    const int tid = threadIdx.x;
    const int wid = tid >> 6;
    const int lane = tid & 63;
    const int wr = wid / WN;
    const int wc = wid % WN;
    const int bm = blockIdx.y * BM;
    const int bn = blockIdx.x * BN;
    const int l15 = lane & 15;
    const int lg = lane >> 4;

    using bf16x8 = __attribute__((ext_vector_type(8))) short;
    using f32x4  = __attribute__((ext_vector_type(4))) float;
    f32x4 acc[MF][NF] = {};

    for (int k0 = 0; k0 < K; k0 += BK) {
        #pragma unroll
        for (int it = 0; it < (BM * BK / 8) / 256; ++it) {
            int v = tid + 256 * it;
            int row = v >> 3;
            int oct = v & 7;
            uint4 val = make_uint4(0, 0, 0, 0);
            int gr = bm + row;
            if (gr < M) {
                if (AF32) {
                    const float* A32 = (const float*)Av;
                    float4 f0 = *(const float4*)(A32 + (size_t)gr * K + k0 + oct * 8);
                    float4 f1 = *(const float4*)(A32 + (size_t)gr * K + k0 + oct * 8 + 4);
                    union { unsigned short u[8]; uint4 v4; } pk;
                    pk.u[0] = f2bf(f0.x); pk.u[1] = f2bf(f0.y);
                    pk.u[2] = f2bf(f0.z); pk.u[3] = f2bf(f0.w);
                    pk.u[4] = f2bf(f1.x); pk.u[5] = f2bf(f1.y);
                    pk.u[6] = f2bf(f1.z); pk.u[7] = f2bf(f1.w);
                    val = pk.v4;
                } else {
                    const unsigned short* Ab = (const unsigned short*)Av;
                    val = *(const uint4*)(Ab + (size_t)gr * K + k0 + oct * 8);
                }
            }
            *(uint4*)(&As[row][oct * 8]) = val;
        }
        #pragma unroll
        for (int it = 0; it < (BN * BK / 8) / 256; ++it) {
            int v = tid + 256 * it;
            int row = v >> 3;
            int oct = v & 7;
            uint4 val = *(const uint4*)(Bt + (size_t)(bn + row) * K + k0 + oct * 8);
            *(uint4*)(&Bs[row][oct * 8]) = val;
        }
        __syncthreads();
        #pragma unroll
        for (int kk = 0; kk < 2; ++kk) {
            bf16x8 af[MF], bfr[NF];
            #pragma unroll
            for (int m = 0; m < MF; ++m)
                af[m] = *(const bf16x8*)(&As[wr * WTM + m * 16 + l15][kk * 32 + lg * 8]);
            #pragma unroll
            for (int nf = 0; nf < NF; ++nf)
                bfr[nf] = *(const bf16x8*)(&Bs[wc * WTN + nf * 16 + l15][kk * 32 + lg * 8]);
            #pragma unroll
            for (int m = 0; m < MF; ++m)
                #pragma unroll
                for (int nf = 0; nf < NF; ++nf)
                    acc[m][nf] = __builtin_amdgcn_mfma_f32_16x16x32_bf16(
                        af[m], bfr[nf], acc[m][nf], 0, 0, 0);
        }
        __syncthreads();
    }
    // C/D layout: col=lane&15, row=(lane>>4)*4+reg  [HW-verified]
    #pragma unroll
    for (int m = 0; m < MF; ++m) {
        #pragma unroll
        for (int j = 0; j < 4; ++j) {
            int row = bm + wr * WTM + m * 16 + lg * 4 + j;
            if (row < M) {
                float s = dinvp[row];
                #pragma unroll
                for (int nf = 0; nf < NF; ++nf) {
                    int col = bn + wc * WTN + nf * 16 + l15;
                    C[(size_t)row * N + col] = f2bf(acc[m][nf][j] * s);
                }
            }
        }
    }
}

// ---- aggregation: block-per-node pull, LDS-staged offsets -----------------
// F=256, hs bf16 in / bf16 out. out[d] = relu(dinv[d]*(hs[d] + Σ hs[s])).
__global__ __launch_bounds__(256) void aggregate256_kernel(
        const unsigned short* __restrict__ hs, const int* __restrict__ rowptr,
        const int* __restrict__ csr, const float* __restrict__ dinv,
        unsigned short* __restrict__ out, int n) {
    const int d = blockIdx.x;
    const int tid = threadIdx.x;
    const int wid = tid >> 6;
    const int lane = tid & 63;
    const int beg = rowptr[d];
    const int end = rowptr[d + 1];

    float acc0 = 0.f, acc1 = 0.f, acc2 = 0.f, acc3 = 0.f;
    if (wid == 0) {   // self-loop: dinv[d]*hs[d] handled by final scale
        ushort4 t = *(const ushort4*)(hs + (size_t)d * 256 + lane * 4);
        acc0 = bf2f(t.x); acc1 = bf2f(t.y); acc2 = bf2f(t.z); acc3 = bf2f(t.w);
    }

    __shared__ unsigned int soff[256];
    const char* hb = (const char*)hs;
    for (int k0 = beg; k0 < end; k0 += 256) {
        int cnt = min(256, end - k0);
        if (tid < cnt) soff[tid] = (unsigned)csr[k0 + tid] * 512u;
        __syncthreads();
        #pragma unroll 8
        for (int e = wid; e < cnt; e += 4) {
            ushort4 t = *(const ushort4*)(hb + soff[e] + lane * 8);
            acc0 += bf2f(t.x); acc1 += bf2f(t.y);
            acc2 += bf2f(t.z); acc3 += bf2f(t.w);
        }
        __syncthreads();
    }

    __shared__ float part[3][256];
    if (wid > 0) {
        part[wid - 1][lane * 4 + 0] = acc0;
        part[wid - 1][lane * 4 + 1] = acc1;
        part[wid - 1][lane * 4 + 2] = acc2;
        part[wid - 1][lane * 4 + 3] = acc3;
    }
    __syncthreads();
    if (wid == 0) {
        const float wd = dinv[d];
        acc0 += part[0][lane*4+0] + part[1][lane*4+0] + part[2][lane*4+0];
        acc1 += part[0][lane*4+1] + part[1][lane*4+1] + part[2][lane*4+1];
        acc2 += part[0][lane*4+2] + part[1][lane*4+2] + part[2][lane*4+2];
        acc3 += part[0][lane*4+3] + part[1][lane*4+3] + part[2][lane*4+3];
        union { unsigned short u[4]; uint2 v; } pk;
        pk.u[0] = f2bf(fmaxf(wd * acc0, 0.f));
        pk.u[1] = f2bf(fmaxf(wd * acc1, 0.f));
        pk.u[2] = f2bf(fmaxf(wd * acc2, 0.f));
        pk.u[3] = f2bf(fmaxf(wd * acc3, 0.f));
        *(uint2*)(out + (size_t)d * 256 + lane * 4) = pk.v;
    }
}

// F=64, hs bf16 in / fp32 out.
__global__ __launch_bounds__(256) void aggregate64_kernel(
        const unsigned short* __restrict__ hs, const int* __restrict__ rowptr,
        const int* __restrict__ csr, const float* __restrict__ dinv,
        float* __restrict__ out, int n) {
    const int d = blockIdx.x;
    const int tid = threadIdx.x;
    const int wid = tid >> 6;
    const int lane = tid & 63;
    const int beg = rowptr[d];
    const int end = rowptr[d + 1];

    float acc = 0.f;
    if (wid == 0) acc = bf2f(hs[(size_t)d * 64 + lane]);   // self-loop

    __shared__ unsigned int soff[256];
    const char* hb = (const char*)hs;
    for (int k0 = beg; k0 < end; k0 += 256) {
        int cnt = min(256, end - k0);
        if (tid < cnt) soff[tid] = (unsigned)csr[k0 + tid] * 128u;
        __syncthreads();
        #pragma unroll 8
        for (int e = wid; e < cnt; e += 4) {
            unsigned short t = *(const unsigned short*)(hb + soff[e] + lane * 2);
            acc += bf2f(t);
        }
        __syncthreads();
    }

    __shared__ float part[3][64];
    if (wid > 0) part[wid - 1][lane] = acc;
    __syncthreads();
    if (wid == 0) {
        acc += part[0][lane] + part[1][lane] + part[2][lane];
        out[(size_t)d * 64 + lane] = fmaxf(dinv[d] * acc, 0.f);
    }
}

// ---------------------------------------------------------------------------

static inline size_t align256(size_t v) { return (v + 255) & ~(size_t)255; }

extern "C" void kernel_launch(void* const* d_in, const int* in_sizes, int n_in,
                              void* d_out, int out_size, void* d_ws, size_t ws_size,
                              hipStream_t stream) {
    const float* x  = (const float*)d_in[0];
    const int*   ei = (const int*)d_in[1];
    const float* W1 = (const float*)d_in[2];
    const float* W3 = (const float*)d_in[3];

    const int n = in_sizes[0] / 256;     // 50000
    const int E = in_sizes[1] / 2;       // 1600000
    const int NB = (n + 63) >> 6;        // 782 buckets
    const int* src = ei;
    const int* dst = ei + E;

    char* w = (char*)d_ws;
    auto alloc = [&](size_t bytes) { char* p = w; w += align256(bytes); return p; };
    unsigned short* hs1  = (unsigned short*)alloc((size_t)n * 256 * 2);
    unsigned short* a1   = (unsigned short*)alloc((size_t)n * 256 * 2);
    unsigned short* hs2  = (unsigned short*)alloc((size_t)n * 64 * 2);
    unsigned short* W1t  = (unsigned short*)alloc(256 * 256 * 2);
    unsigned short* W3t  = (unsigned short*)alloc(64 * 256 * 2);
    float* dinv          = (float*)alloc((size_t)n * 4);
    int*   rowptr        = (int*)alloc((size_t)(n + 1) * 4);
    int*   csr           = (int*)alloc((size_t)E * 4);
    unsigned int* words  = (unsigned int*)alloc((size_t)E * 4);
    int*   blockhist     = (int*)alloc((size_t)NPART * NB * 4);
    int*   bbase         = (int*)alloc((size_t)NPART * NB * 4);
    int*   bofs          = (int*)alloc((size_t)(NB + 1) * 4);
    float* out           = (float*)d_out;

    wcvt2_kernel<<<(256 * 256 + 64 * 256 + 255) / 256, 256, 0, stream>>>(W1, W3, W1t, W3t);

    part_hist<<<NPART, 256, 0, stream>>>(dst, E, NB, blockhist);
    part_scan<<<1, 1024, 0, stream>>>(blockhist, bofs, bbase, NB);
    part_scatter<<<NPART, 256, 0, stream>>>(src, dst, bbase, words, E, NB);
    bucket_build<<<NB, 256, 0, stream>>>(words, bofs, rowptr, dinv, csr, n);

    // layer 1: hs1 = bf16((x @ W1)·dinv); a1 = relu-agg (bf16)
    {
        dim3 grid(1, (n + 127) / 128);
        mfma_gemm<256, 2, 2, true><<<grid, 256, 0, stream>>>(x, W1t, dinv, hs1, n, 256, 256);
        aggregate256_kernel<<<n, 256, 0, stream>>>(hs1, rowptr, csr, dinv, a1, n);
    }
    // layer 2: hs2 = bf16((a1 @ W3)·dinv); out = relu-agg (fp32)
    {
        dim3 grid(1, (n + 127) / 128);
        mfma_gemm<64, 4, 1, false><<<grid, 256, 0, stream>>>(a1, W3t, dinv, hs2, n, 64, 256);
        aggregate64_kernel<<<n, 256, 0, stream>>>(hs2, rowptr, csr, dinv, out, n);
    }
}